// Round 7
// baseline (141.492 us; speedup 1.0000x reference)
//
#include <hip/hip_runtime.h>
#include <stdint.h>

#define BATCH 16
#define NQ    2048
#define NK    2048
#define DD    128
#define DVV   128

typedef __bf16 bf16_t;
typedef __bf16 bf16x2 __attribute__((ext_vector_type(2)));
typedef __bf16 bf16x4 __attribute__((ext_vector_type(4)));
typedef __bf16 bf16x8 __attribute__((ext_vector_type(8)));
typedef float  f32x4  __attribute__((ext_vector_type(4)));

// ---------------- ws layout (bytes) ----------------
#define KB_OFF   ((size_t)0)                 // bf16 K: 8 MB
#define VT_OFF   ((size_t)8 * 1024 * 1024)   // bf16 V^T [b][dv][k]: 8 MB
#define SUF_OFF  ((size_t)16 * 1024 * 1024)  // fp32 sufV[b][dv]: 8 KB
#define SCH_OFF  (SUF_OFF + 65536)           // int schedule[512]
#define WS_NEED  (SCH_OFF + 4096)

__device__ __forceinline__ int load_valid_len(const int* VL, int b) {
  bool looks64 = true;
#pragma unroll
  for (int i = 0; i < 16; ++i) {
    int hi = VL[2 * i + 1];
    unsigned lo = (unsigned)VL[2 * i];
    looks64 = looks64 && (hi == 0) && (lo <= 2048u);
  }
  int L = looks64 ? VL[2 * b] : VL[b];
  return min(max(L, 0), NK);
}

__device__ __forceinline__ void gld16(const void* g, void* l) {
  __builtin_amdgcn_global_load_lds(
      (const __attribute__((address_space(1))) unsigned int*)g,
      (__attribute__((address_space(3))) unsigned int*)l, 16, 0, 0);
}

__device__ __forceinline__ f32x4 mfma16(bf16x8 a, bf16x8 b, f32x4 c) {
  return __builtin_amdgcn_mfma_f32_16x16x32_bf16(a, b, c, 0, 0, 0);
}

// ---------------- fused preprocessing ----------------
// blocks 0..511  : K fp32 -> bf16 (coalesced, lane-interleaved)
// blocks 512..1023: V fp32 [b][k][dv] -> bf16 V^T [b][dv][k] + masked-suffix sums
// block 1024     : schedule = units sorted by batch L descending (LPT)
__global__ void prep_kernel(const float* __restrict__ K, const float* __restrict__ V,
                            const int* __restrict__ VL,
                            bf16_t* __restrict__ Kb, bf16_t* __restrict__ Vt,
                            float* __restrict__ sufV, int* __restrict__ sched) {
  __shared__ bf16_t tile[128 * 72];  // [dv][key] stride 72
  __shared__ int bs[16];
  const int bid = blockIdx.x;
  const int t = threadIdx.x;
  if (bid < 512) {
    // ---- K convert: thread owns float4 pair (2t,2t+1) of 512-float4 chunks ----
#pragma unroll
    for (int i = 0; i < 4; ++i) {
      size_t f4 = (size_t)bid * 2048 + (size_t)i * 512 + 2 * t;
      float4 a = ((const float4*)K)[f4];
      float4 c = ((const float4*)K)[f4 + 1];
      bf16x8 o;
      o[0] = (bf16_t)a.x; o[1] = (bf16_t)a.y; o[2] = (bf16_t)a.z; o[3] = (bf16_t)a.w;
      o[4] = (bf16_t)c.x; o[5] = (bf16_t)c.y; o[6] = (bf16_t)c.z; o[7] = (bf16_t)c.w;
      ((bf16x8*)Kb)[f4 >> 1] = o;
    }
    return;
  }
  if (bid < 1024) {
    // ---- vtrans (proven path) ----
    int v = bid - 512;
    int b = v & 15, kt = v >> 4;
    int L = load_valid_len(VL, b);
    int m = t & 31;   // key-pair 0..31
    int g = t >> 5;   // dv group 0..7
    int r2 = m * 2;
    int k0g = kt * 64 + r2;
    const float* src = V + ((size_t)b * NK + k0g) * DVV;
    float sacc[4][4];
#pragma unroll
    for (int i = 0; i < 4; ++i)
#pragma unroll
      for (int j = 0; j < 4; ++j) sacc[i][j] = 0.f;
    bool a0 = (k0g >= L), a1 = (k0g + 1 >= L);
#pragma unroll
    for (int i = 0; i < 4; ++i) {
      int d4 = g * 4 + i * 32;
      float4 u0 = *(const float4*)(src + d4);
      float4 u1 = *(const float4*)(src + DVV + d4);
      *(bf16x2*)&tile[(d4 + 0) * 72 + r2] = (bf16x2){(bf16_t)u0.x, (bf16_t)u1.x};
      *(bf16x2*)&tile[(d4 + 1) * 72 + r2] = (bf16x2){(bf16_t)u0.y, (bf16_t)u1.y};
      *(bf16x2*)&tile[(d4 + 2) * 72 + r2] = (bf16x2){(bf16_t)u0.z, (bf16_t)u1.z};
      *(bf16x2*)&tile[(d4 + 3) * 72 + r2] = (bf16x2){(bf16_t)u0.w, (bf16_t)u1.w};
      if (a0) { sacc[i][0] += u0.x; sacc[i][1] += u0.y; sacc[i][2] += u0.z; sacc[i][3] += u0.w; }
      if (a1) { sacc[i][0] += u1.x; sacc[i][1] += u1.y; sacc[i][2] += u1.z; sacc[i][3] += u1.w; }
    }
    __syncthreads();
#pragma unroll
    for (int off = 1; off < 32; off <<= 1)
#pragma unroll
      for (int i = 0; i < 4; ++i)
#pragma unroll
        for (int j = 0; j < 4; ++j) sacc[i][j] += __shfl_xor(sacc[i][j], off, 64);
    if (m == 0) {
#pragma unroll
      for (int i = 0; i < 4; ++i)
#pragma unroll
        for (int j = 0; j < 4; ++j)
          atomicAdd(&sufV[b * 128 + g * 4 + i * 32 + j], sacc[i][j]);
    }
    int dv = t >> 1, half = t & 1;
    bf16_t* dst = Vt + (size_t)b * DVV * NK + (size_t)dv * NK + kt * 64 + half * 32;
    const bf16_t* srow = &tile[dv * 72 + half * 32];
#pragma unroll
    for (int j = 0; j < 4; ++j)
      *(bf16x8*)(dst + j * 8) = *(const bf16x8*)(srow + j * 8);
    return;
  }
  // ---- schedule block: descending-L order (LPT) ----
  if (t == 0) {
    int Ls[16], idx[16];
#pragma unroll
    for (int i = 0; i < 16; ++i) { Ls[i] = load_valid_len(VL, i); idx[i] = i; }
    for (int i = 1; i < 16; ++i) {       // insertion sort desc by L
      int lv = Ls[i], iv = idx[i], j = i - 1;
      while (j >= 0 && Ls[j] < lv) { Ls[j + 1] = Ls[j]; idx[j + 1] = idx[j]; --j; }
      Ls[j + 1] = lv; idx[j + 1] = iv;
    }
#pragma unroll
    for (int i = 0; i < 16; ++i) bs[i] = idx[i];
  }
  __syncthreads();
  for (int j = t; j < 512; j += 256)
    sched[j] = (bs[j >> 5] << 5) | (j & 31);
}

// ---------------- main attention ----------------
// 512 threads = 8 waves = 4 q-groups (16q) x 2 key-halves (32k) over a 64q x 64k tile.
// SWAPPED QK^T: S^T = mfma(K_frag, Q_frag) puts each q-row's P lane-local (q = lane&15).
// P never touches LDS: packed to bf16 pairs in-reg, redistributed to the PV A-fragment
// layout via 8 ds_bpermute (__shfl) + 4 selects. Fixed-ref exp2 softmax; 2-way key-half
// merge via LDS scratch (aliases dead sK/sV). LDS 65KB -> 2 blocks/CU (16 waves).
__launch_bounds__(512, 4)
__global__ void attn_kernel(const float* __restrict__ Q, const bf16_t* __restrict__ Kb,
                            const bf16_t* __restrict__ Vt, const int* __restrict__ VL,
                            const float* __restrict__ sufV, const int* __restrict__ sched,
                            float* __restrict__ Out) {
  __shared__ __align__(16) char smem[66560];
  bf16_t* sK = (bf16_t*)smem;                     // [2][64*128]
  bf16_t* sV = (bf16_t*)(smem + 32768);           // [2][128*64] (V^T tile)

  const int unit = sched[blockIdx.x];
  const int b  = (unit >> 5) & 15;
  const int qt = unit & 31;
  const int L  = load_valid_len(VL, b);
  const int ktiles = (L + 63) >> 6;

  const int tid = threadIdx.x;
  const int wave = tid >> 6;   // 0..7
  const int lane = tid & 63;
  const int col = lane & 15;
  const int quad = lane >> 4;
  const int qg = wave >> 1;    // q-16-group 0..3
  const int kg = wave & 1;     // key-half

  // Q fragments: fp32 -> bf16 in-reg, scaled by log2(e)/sqrt(128) (log2 domain).
  // Layout = B-operand for swapped QK: lane holds Q[q=col][d=quad*8.. per ks-chunk].
  bf16x8 qf[4];
  {
    const float scq = 0.1275174307f;
    const float* qrow = Q + ((size_t)b * NQ + qt * 64 + qg * 16 + col) * DD + quad * 8;
#pragma unroll
    for (int ks = 0; ks < 4; ++ks) {
      float4 u0 = *(const float4*)(qrow + ks * 32);
      float4 u1 = *(const float4*)(qrow + ks * 32 + 4);
      bf16x8 f;
      f[0] = (bf16_t)(u0.x * scq); f[1] = (bf16_t)(u0.y * scq);
      f[2] = (bf16_t)(u0.z * scq); f[3] = (bf16_t)(u0.w * scq);
      f[4] = (bf16_t)(u1.x * scq); f[5] = (bf16_t)(u1.y * scq);
      f[6] = (bf16_t)(u1.z * scq); f[7] = (bf16_t)(u1.w * scq);
      qf[ks] = f;
    }
  }

  const char* Kbyte = (const char*)Kb + (size_t)b * NK * DD * 2;
  const char* Vbyte = (const char*)Vt + (size_t)b * DVV * NK * 2;
  int koff[2], voff[2];
#pragma unroll
  for (int i = 0; i < 2; ++i) {
    int krow = wave * 8 + i * 4 + quad;               // 0..63 key row
    koff[i] = krow * 256 + (((lane & 15) ^ (krow & 15)) * 16);
    int vrow = wave * 16 + i * 8 + (lane >> 3);       // 0..127 dv row
    voff[i] = vrow * (NK * 2) + (((lane & 7) ^ (vrow & 7)) * 16);
  }

  f32x4 Oacc[8];   // [o dv-tile]: O[q=quad*4+r][dv=o*16+col], this wave's 32 keys
#pragma unroll
  for (int o = 0; o < 8; ++o) Oacc[o] = (f32x4){0.f, 0.f, 0.f, 0.f};
  float lsum = 0.f;   // per-lane partial l for q = col (keys quad*4+r per nt)

  auto issueTile = [&](int kt, int bufi) {
    const char* kb = Kbyte + (size_t)kt * 16384;
    const char* vb = Vbyte + (size_t)kt * 128;
    bf16_t* kl = sK + bufi * 8192 + wave * 1024;
    bf16_t* vl = sV + bufi * 8192 + wave * 1024;
#pragma unroll
    for (int i = 0; i < 2; ++i) {
      gld16(kb + koff[i], kl + i * 512);
      gld16(vb + voff[i], vl + i * 512);
    }
  };

  if (ktiles > 0) issueTile(0, 0);
  int bufi = 0;
  for (int kt = 0; kt < ktiles; ++kt) {
    if (kt + 1 < ktiles) {
      issueTile(kt + 1, bufi ^ 1);
      asm volatile("s_waitcnt vmcnt(4)\n\ts_barrier" ::: "memory");
    } else {
      asm volatile("s_waitcnt vmcnt(0)\n\ts_barrier" ::: "memory");
    }

    const bf16_t* kb_ = sK + bufi * 8192;
    const bf16_t* vb_ = sV + bufi * 8192;

    // S^T = K Q^T (log2 domain): D[row=key (quad,r)][col=q]. The kb_ read is a valid
    // A-fragment (rows = keys), qf a valid B-fragment (cols = q) -- same addresses.
    f32x4 sc[2];
#pragma unroll
    for (int nt = 0; nt < 2; ++nt) sc[nt] = (f32x4){0.f, 0.f, 0.f, 0.f};
    __builtin_amdgcn_s_setprio(1);
#pragma unroll
    for (int ks = 0; ks < 4; ++ks) {
#pragma unroll
      for (int nt = 0; nt < 2; ++nt) {
        bf16x8 kf = *(const bf16x8*)&kb_[(kg * 32 + nt * 16 + col) * 128 + (((ks * 4 + quad) ^ col) * 8)];
        sc[nt] = mfma16(kf, qf[ks], sc[nt]);
      }
    }
    __builtin_amdgcn_s_setprio(0);

    // p = 2^S, mask (key = base + nt*16 + quad*4 + r), lane-local l accum (q=col),
    // pack to bf16 pairs in-register (no LDS).
    const int key0 = kt * 64 + kg * 32 + quad * 4;
    unsigned pk[2][2];
#pragma unroll
    for (int nt = 0; nt < 2; ++nt) {
      float pv[4];
#pragma unroll
      for (int r = 0; r < 4; ++r) {
        float p = __builtin_amdgcn_exp2f(sc[nt][r]);
        p = (key0 + nt * 16 + r < L) ? p : 0.f;
        lsum += p;
        pv[r] = p;
      }
      union { bf16x2 h; unsigned u; } c0, c1;
      c0.h = (bf16x2){(bf16_t)pv[0], (bf16_t)pv[1]};
      c1.h = (bf16x2){(bf16_t)pv[2], (bf16_t)pv[3]};
      pk[nt][0] = c0.u;
      pk[nt][1] = c1.u;
    }

    // Assemble PV A-fragment in-register: lane needs P[q=col][k=quad*8+j].
    // Source lane for key-pair j2: col + 32*(quad&1) (+16 for j2>=2); value pk[quad>>1][j2&1].
    {
      int sl0 = col + ((quad & 1) << 5);
      int hi = quad >> 1;
      unsigned a00 = __shfl((int)pk[0][0], sl0, 64);
      unsigned a01 = __shfl((int)pk[0][1], sl0, 64);
      unsigned a10 = __shfl((int)pk[1][0], sl0, 64);
      unsigned a11 = __shfl((int)pk[1][1], sl0, 64);
      unsigned b00 = __shfl((int)pk[0][0], sl0 + 16, 64);
      unsigned b01 = __shfl((int)pk[0][1], sl0 + 16, 64);
      unsigned b10 = __shfl((int)pk[1][0], sl0 + 16, 64);
      unsigned b11 = __shfl((int)pk[1][1], sl0 + 16, 64);
      union { unsigned u[4]; bf16x8 v; } pa;
      pa.u[0] = hi ? a10 : a00;
      pa.u[1] = hi ? a11 : a01;
      pa.u[2] = hi ? b10 : b00;
      pa.u[3] = hi ? b11 : b01;

      // O += P V over this wave's 32 keys
      __builtin_amdgcn_s_setprio(1);
#pragma unroll
      for (int o = 0; o < 8; ++o) {
        bf16x8 bb = *(const bf16x8*)&vb_[(o * 16 + col) * 64 + (((kg * 4 + quad) ^ (col & 7)) * 8)];
        Oacc[o] = mfma16(pa.v, bb, Oacc[o]);
      }
      __builtin_amdgcn_s_setprio(0);
    }
    asm volatile("s_barrier" ::: "memory");
    bufi ^= 1;
  }

  // reduce l across the 4 quads sharing each q (lane-local per col)
  lsum += __shfl_xor(lsum, 16, 64);
  lsum += __shfl_xor(lsum, 32, 64);

  // ---- cross-wave (key-half) merge via LDS scratch (aliases dead sK/sV) ----
  // scrO per qg: [dv 0..127][q 0..15] f32, row stride 20 words (80B) -> 10240B each
  float* scrO = (float*)smem + qg * 2560;
  float* scrL = (float*)(smem + 65536) + qg * 16;

  if (kg) {
#pragma unroll
    for (int o = 0; o < 8; ++o)
      *(f32x4*)&scrO[(o * 16 + col) * 20 + quad * 4] = Oacc[o];
    if (quad == 0) scrL[col] = lsum;
  }
  __syncthreads();
  if (!kg) {
    // epilogue: masked-suffix closed form (e^{1e-8}==1.0f) + divide + direct store
    const float wmask = (float)(NK - L);
    float inv = 1.0f / (lsum + scrL[col] + wmask);   // inv for q = col
    float invq[4];
#pragma unroll
    for (int r = 0; r < 4; ++r)
      invq[r] = __shfl(inv, quad * 4 + r, 64);       // inv for q = quad*4+r
    const float* sfv = sufV + b * DVV;
    float* Ob = Out + ((size_t)b * NQ + qt * 64 + qg * 16) * DVV;
#pragma unroll
    for (int o = 0; o < 8; ++o) {
      f32x4 part = *(const f32x4*)&scrO[(o * 16 + col) * 20 + quad * 4];
      float svv = sfv[o * 16 + col];
#pragma unroll
      for (int r = 0; r < 4; ++r)
        Ob[(size_t)(quad * 4 + r) * DVV + o * 16 + col] =
            (Oacc[o][r] + part[r] + svv) * invq[r];
    }
  }
}

// ================= fallback path (round-1 kernel) if ws too small =================
#define KSTR 152
#define VSTR 88
#define PSTR 72

__global__ void suffix_fb(const float* __restrict__ V, const int* __restrict__ VL,
                          float* __restrict__ ws) {
  int b = blockIdx.x;
  int kc = blockIdx.y;
  int L = load_valid_len(VL, b);
  int k0 = kc * 128, k1 = k0 + 128;
  int lo = max(L, k0);
  int t = threadIdx.x;
  int dv = t & 127;
  int h = t >> 7;
  float s = 0.f;
  for (int k = lo + h; k < k1; k += 2)
    s += V[((size_t)b * NK + k) * DVV + dv];
  __shared__ float part[128];
  if (h == 0) part[dv] = s;
  __syncthreads();
  if (h == 1) atomicAdd(&ws[b * DVV + dv], part[dv] + s);
}

__launch_bounds__(256, 2)
__global__ void attn_fb(const float* __restrict__ Q, const float* __restrict__ K,
                        const float* __restrict__ V, const int* __restrict__ VL,
                        const float* __restrict__ sufV, float* __restrict__ Out) {
  const int flat = blockIdx.x;
  const int b  = flat & 15;
  const int qt = flat >> 4;
  const int L  = load_valid_len(VL, b);

  __shared__ bf16_t sK2[64 * KSTR];
  __shared__ bf16_t sVT2[128 * VSTR];
  __shared__ bf16_t sP2[4 * 16 * PSTR];

  const int tid  = threadIdx.x;
  const int wave = tid >> 6;
  const int lane = tid & 63;
  const int col  = lane & 15;
  const int quad = lane >> 4;

  const float* Qb = Q + ((size_t)b * NQ + qt * 64 + wave * 16) * DD;
  const float* Kb = K + (size_t)b * NK * DD;
  const float* Vb = V + (size_t)b * NK * DVV;

  bf16x8 qf[4];
  {
    const float scq = 0.08838834764831845f;
    const float* qrow = Qb + (size_t)col * DD + quad * 8;
#pragma unroll
    for (int ks = 0; ks < 4; ++ks) {
      float4 u0 = *(const float4*)(qrow + ks * 32);
      float4 u1 = *(const float4*)(qrow + ks * 32 + 4);
      bf16x8 f;
      f[0] = (bf16_t)(u0.x * scq); f[1] = (bf16_t)(u0.y * scq);
      f[2] = (bf16_t)(u0.z * scq); f[3] = (bf16_t)(u0.w * scq);
      f[4] = (bf16_t)(u1.x * scq); f[5] = (bf16_t)(u1.y * scq);
      f[6] = (bf16_t)(u1.z * scq); f[7] = (bf16_t)(u1.w * scq);
      qf[ks] = f;
    }
  }

  f32x4 Oacc[8];
#pragma unroll
  for (int o = 0; o < 8; ++o) Oacc[o] = (f32x4){0.f, 0.f, 0.f, 0.f};
  float m_i[4], l_i[4];
#pragma unroll
  for (int r = 0; r < 4; ++r) { m_i[r] = -1e30f; l_i[r] = 0.f; }

  const int ktiles = (L + 63) >> 6;
  for (int kt = 0; kt < ktiles; ++kt) {
    {
      int r0 = tid >> 5;
      int d4 = (tid & 31) * 4;
      const float* src = Kb + ((size_t)(kt * 64) + r0) * DD + d4;
#pragma unroll
      for (int i = 0; i < 8; ++i) {
        float4 u = *(const float4*)(src + (size_t)i * 8 * DD);
        bf16x4 w4 = {(bf16_t)u.x, (bf16_t)u.y, (bf16_t)u.z, (bf16_t)u.w};
        *(bf16x4*)&sK2[(r0 + i * 8) * KSTR + d4] = w4;
      }
    }
    {
      int r2 = (tid & 31) * 2;
      int dbase = (tid >> 5) * 4;
#pragma unroll
      for (int i = 0; i < 4; ++i) {
        int d4 = dbase + i * 32;
        const float* s0 = Vb + ((size_t)(kt * 64) + r2) * DVV + d4;
        float4 u0 = *(const float4*)s0;
        float4 u1 = *(const float4*)(s0 + DVV);
        *(bf16x2*)&sVT2[(d4 + 0) * VSTR + r2] = (bf16x2){(bf16_t)u0.x, (bf16_t)u1.x};
        *(bf16x2*)&sVT2[(d4 + 1) * VSTR + r2] = (bf16x2){(bf16_t)u0.y, (bf16_t)u1.y};
        *(bf16x2*)&sVT2[(d4 + 2) * VSTR + r2] = (bf16x2){(bf16_t)u0.z, (bf16_t)u1.z};
        *(bf16x2*)&sVT2[(d4 + 3) * VSTR + r2] = (bf16x2){(bf16_t)u0.w, (bf16_t)u1.w};
      }
    }
    __syncthreads();

    f32x4 sv4[4];
#pragma unroll
    for (int nt = 0; nt < 4; ++nt) sv4[nt] = (f32x4){0.f, 0.f, 0.f, 0.f};
#pragma unroll
    for (int ks = 0; ks < 4; ++ks) {
      bf16x8 a = qf[ks];
#pragma unroll
      for (int nt = 0; nt < 4; ++nt) {
        bf16x8 bb = *(const bf16x8*)&sK2[(nt * 16 + col) * KSTR + ks * 32 + quad * 8];
        sv4[nt] = mfma16(a, bb, sv4[nt]);
      }
    }

    const int key0 = kt * 64;
    float sv[4][4];
    float mloc[4] = {-1e30f, -1e30f, -1e30f, -1e30f};
#pragma unroll
    for (int nt = 0; nt < 4; ++nt) {
      int key = key0 + nt * 16 + col;
      bool valid = key < L;
#pragma unroll
      for (int r = 0; r < 4; ++r) {
        float v = valid ? sv4[nt][r] : -1e30f;
        sv[nt][r] = v;
        mloc[r] = fmaxf(mloc[r], v);
      }
    }
#pragma unroll
    for (int off = 1; off < 16; off <<= 1)
#pragma unroll
      for (int r = 0; r < 4; ++r) mloc[r] = fmaxf(mloc[r], __shfl_xor(mloc[r], off, 64));
    float al[4];
#pragma unroll
    for (int r = 0; r < 4; ++r) {
      float mn = fmaxf(m_i[r], mloc[r]);
      al[r] = __expf(m_i[r] - mn);
      m_i[r] = mn;
    }
    float lloc[4] = {0.f, 0.f, 0.f, 0.f};
#pragma unroll
    for (int nt = 0; nt < 4; ++nt)
#pragma unroll
      for (int r = 0; r < 4; ++r) {
        float p = __expf(sv[nt][r] - m_i[r]);
        sv[nt][r] = p;
        lloc[r] += p;
      }
#pragma unroll
    for (int off = 1; off < 16; off <<= 1)
#pragma unroll
      for (int r = 0; r < 4; ++r) lloc[r] += __shfl_xor(lloc[r], off, 64);
#pragma unroll
    for (int r = 0; r < 4; ++r) l_i[r] = l_i[r] * al[r] + lloc[r];
#pragma unroll
    for (int o = 0; o < 8; ++o)
#pragma unroll
      for (int r = 0; r < 4; ++r) Oacc[o][r] *= al[r];

    bf16_t* pw = &sP2[wave * 16 * PSTR];
#pragma unroll
    for (int nt = 0; nt < 4; ++nt)
#pragma unroll
      for (int r = 0; r < 4; ++r)
        pw[(quad * 4 + r) * PSTR + nt * 16 + col] = (bf16_t)sv[nt][r];

#pragma unroll
    for (int ks2 = 0; ks2 < 2; ++ks2) {
      bf16x8 a = *(const bf16x8*)&pw[(lane & 15) * PSTR + ks2 * 32 + quad * 8];
#pragma unroll
      for (int o = 0; o < 8; ++o) {
        bf16x8 bb = *(const bf16x8*)&sVT2[(o * 16 + col) * VSTR + ks2 * 32 + quad * 8];
        Oacc[o] = mfma16(a, bb, Oacc[o]);
      }
    }
    __syncthreads();
  }

  if (L < NK) {
    const float c = 1e-8f;
    const float w = (float)(NK - L);
    float a2[4], ec[4];
#pragma unroll
    for (int r = 0; r < 4; ++r) {
      float mn = fmaxf(m_i[r], c);
      a2[r] = __expf(m_i[r] - mn);
      ec[r] = __expf(c - mn);
      l_i[r] = l_i[r] * a2[r] + w * ec[r];
    }
    const float* sfv = sufV + b * DVV;
#pragma unroll
    for (int o = 0; o < 8; ++o) {
      float svv = sfv[o * 16 + col];
#pragma unroll
      for (int r = 0; r < 4; ++r) Oacc[o][r] = Oacc[o][r] * a2[r] + ec[r] * svv;
    }
  }

  float invl[4];
#pragma unroll
  for (int r = 0; r < 4; ++r) invl[r] = 1.0f / l_i[r];

  float* Ob = Out + ((size_t)b * NQ + qt * 64 + wave * 16) * DVV;
#pragma unroll
  for (int o = 0; o < 8; ++o)
#pragma unroll
    for (int r = 0; r < 4; ++r)
      Ob[(size_t)(quad * 4 + r) * DVV + o * 16 + col] = Oacc[o][r] * invl[r];
}

extern "C" void kernel_launch(void* const* d_in, const int* in_sizes, int n_in,
                              void* d_out, int out_size, void* d_ws, size_t ws_size,
                              hipStream_t stream) {
  const float* Q  = (const float*)d_in[0];
  const float* K  = (const float*)d_in[1];
  const float* V  = (const float*)d_in[2];
  const int*   VL = (const int*)d_in[3];
  float* out = (float*)d_out;

  if (ws_size >= WS_NEED) {
    char* ws = (char*)d_ws;
    bf16_t* Kb = (bf16_t*)(ws + KB_OFF);
    bf16_t* Vt = (bf16_t*)(ws + VT_OFF);
    float* sufV = (float*)(ws + SUF_OFF);
    int* sched = (int*)(ws + SCH_OFF);

    hipMemsetAsync(sufV, 0, BATCH * DVV * sizeof(float), stream);
    prep_kernel<<<1025, 256, 0, stream>>>(K, V, VL, Kb, Vt, sufV, sched);
    attn_kernel<<<512, 512, 0, stream>>>(Q, Kb, Vt, VL, sufV, sched, out);
  } else {
    float* ws = (float*)d_ws;
    hipMemsetAsync(ws, 0, BATCH * DVV * sizeof(float), stream);
    dim3 g1(BATCH, 16);
    suffix_fb<<<g1, 256, 0, stream>>>(V, VL, ws);
    attn_fb<<<BATCH * (NQ / 64), 256, 0, stream>>>(Q, K, V, VL, ws, out);
  }
}

// Round 8
// 136.715 us; speedup vs baseline: 1.0349x; 1.0349x over previous
//
#include <hip/hip_runtime.h>
#include <stdint.h>

#define BATCH 16
#define NQ    2048
#define NK    2048
#define DD    128
#define DVV   128

typedef __bf16 bf16_t;
typedef __bf16 bf16x2 __attribute__((ext_vector_type(2)));
typedef __bf16 bf16x4 __attribute__((ext_vector_type(4)));
typedef __bf16 bf16x8 __attribute__((ext_vector_type(8)));
typedef float  f32x4  __attribute__((ext_vector_type(4)));

// ---------------- ws layout (bytes) ----------------
#define KB_OFF   ((size_t)0)                 // bf16 K: 8 MB
#define VT_OFF   ((size_t)8 * 1024 * 1024)   // bf16 V^T [b][dv][k]: 8 MB
#define SUF_OFF  ((size_t)16 * 1024 * 1024)  // fp32 sufV[b][dv]: 8 KB
#define SCH_OFF  (SUF_OFF + 65536)           // int schedule[512]
#define WS_NEED  (SCH_OFF + 4096)

__device__ __forceinline__ int load_valid_len(const int* VL, int b) {
  bool looks64 = true;
#pragma unroll
  for (int i = 0; i < 16; ++i) {
    int hi = VL[2 * i + 1];
    unsigned lo = (unsigned)VL[2 * i];
    looks64 = looks64 && (hi == 0) && (lo <= 2048u);
  }
  int L = looks64 ? VL[2 * b] : VL[b];
  return min(max(L, 0), NK);
}

__device__ __forceinline__ void gld16(const void* g, void* l) {
  __builtin_amdgcn_global_load_lds(
      (const __attribute__((address_space(1))) unsigned int*)g,
      (__attribute__((address_space(3))) unsigned int*)l, 16, 0, 0);
}

__device__ __forceinline__ f32x4 mfma16(bf16x8 a, bf16x8 b, f32x4 c) {
  return __builtin_amdgcn_mfma_f32_16x16x32_bf16(a, b, c, 0, 0, 0);
}

// ---------------- fused preprocessing ----------------
// blocks 0..511  : K fp32 -> bf16 (coalesced, lane-interleaved)
// blocks 512..1023: V fp32 [b][k][dv] -> bf16 V^T [b][dv][k] + masked-suffix sums
// block 1024     : snake schedule (batches sorted by L desc)
__global__ void prep_kernel(const float* __restrict__ K, const float* __restrict__ V,
                            const int* __restrict__ VL,
                            bf16_t* __restrict__ Kb, bf16_t* __restrict__ Vt,
                            float* __restrict__ sufV, int* __restrict__ sched) {
  __shared__ bf16_t tile[128 * 72];  // [dv][key] stride 72
  __shared__ int bs[16];
  const int bid = blockIdx.x;
  const int t = threadIdx.x;
  if (bid < 512) {
    // ---- K convert: thread owns float4 pair (2t,2t+1) of 512-float4 chunks ----
#pragma unroll
    for (int i = 0; i < 4; ++i) {
      size_t f4 = (size_t)bid * 2048 + (size_t)i * 512 + 2 * t;
      float4 a = ((const float4*)K)[f4];
      float4 c = ((const float4*)K)[f4 + 1];
      bf16x8 o;
      o[0] = (bf16_t)a.x; o[1] = (bf16_t)a.y; o[2] = (bf16_t)a.z; o[3] = (bf16_t)a.w;
      o[4] = (bf16_t)c.x; o[5] = (bf16_t)c.y; o[6] = (bf16_t)c.z; o[7] = (bf16_t)c.w;
      ((bf16x8*)Kb)[f4 >> 1] = o;
    }
    return;
  }
  if (bid < 1024) {
    // ---- vtrans (proven path) ----
    int v = bid - 512;
    int b = v & 15, kt = v >> 4;
    int L = load_valid_len(VL, b);
    int m = t & 31;   // key-pair 0..31
    int g = t >> 5;   // dv group 0..7
    int r2 = m * 2;
    int k0g = kt * 64 + r2;
    const float* src = V + ((size_t)b * NK + k0g) * DVV;
    float sacc[4][4];
#pragma unroll
    for (int i = 0; i < 4; ++i)
#pragma unroll
      for (int j = 0; j < 4; ++j) sacc[i][j] = 0.f;
    bool a0 = (k0g >= L), a1 = (k0g + 1 >= L);
#pragma unroll
    for (int i = 0; i < 4; ++i) {
      int d4 = g * 4 + i * 32;
      float4 u0 = *(const float4*)(src + d4);
      float4 u1 = *(const float4*)(src + DVV + d4);
      *(bf16x2*)&tile[(d4 + 0) * 72 + r2] = (bf16x2){(bf16_t)u0.x, (bf16_t)u1.x};
      *(bf16x2*)&tile[(d4 + 1) * 72 + r2] = (bf16x2){(bf16_t)u0.y, (bf16_t)u1.y};
      *(bf16x2*)&tile[(d4 + 2) * 72 + r2] = (bf16x2){(bf16_t)u0.z, (bf16_t)u1.z};
      *(bf16x2*)&tile[(d4 + 3) * 72 + r2] = (bf16x2){(bf16_t)u0.w, (bf16_t)u1.w};
      if (a0) { sacc[i][0] += u0.x; sacc[i][1] += u0.y; sacc[i][2] += u0.z; sacc[i][3] += u0.w; }
      if (a1) { sacc[i][0] += u1.x; sacc[i][1] += u1.y; sacc[i][2] += u1.z; sacc[i][3] += u1.w; }
    }
    __syncthreads();
#pragma unroll
    for (int off = 1; off < 32; off <<= 1)
#pragma unroll
      for (int i = 0; i < 4; ++i)
#pragma unroll
        for (int j = 0; j < 4; ++j) sacc[i][j] += __shfl_xor(sacc[i][j], off, 64);
    if (m == 0) {
#pragma unroll
      for (int i = 0; i < 4; ++i)
#pragma unroll
        for (int j = 0; j < 4; ++j)
          atomicAdd(&sufV[b * 128 + g * 4 + i * 32 + j], sacc[i][j]);
    }
    int dv = t >> 1, half = t & 1;
    bf16_t* dst = Vt + (size_t)b * DVV * NK + (size_t)dv * NK + kt * 64 + half * 32;
    const bf16_t* srow = &tile[dv * 72 + half * 32];
#pragma unroll
    for (int j = 0; j < 4; ++j)
      *(bf16x8*)(dst + j * 8) = *(const bf16x8*)(srow + j * 8);
    return;
  }
  // ---- schedule block ----
  if (t == 0) {
    int Ls[16], idx[16];
#pragma unroll
    for (int i = 0; i < 16; ++i) { Ls[i] = load_valid_len(VL, i); idx[i] = i; }
    for (int i = 1; i < 16; ++i) {       // insertion sort desc by L
      int lv = Ls[i], iv = idx[i], j = i - 1;
      while (j >= 0 && Ls[j] < lv) { Ls[j + 1] = Ls[j]; idx[j + 1] = idx[j]; --j; }
      Ls[j + 1] = lv; idx[j + 1] = iv;
    }
#pragma unroll
    for (int i = 0; i < 16; ++i) bs[i] = idx[i];
  }
  __syncthreads();
  for (int j = t; j < 512; j += 256) {
    int r = (j < 256) ? j : (767 - j);    // snake pairing: blocks j, j+256 share a CU slot
    sched[j] = (bs[r >> 5] << 5) | (r & 31);
  }
}

// ---------------- main attention ----------------
// 2x2 wave tiling (32q x 32k per wave). SWAPPED QK^T (r7-proven): S^T = mfma(K,Q) puts
// 4 consecutive-key P values per lane -> P store is 4x ds_write_b64 into r3's proven
// chunk-XOR P layout (was 16x ds_write_b16 scatter). LDS instr/wave-iter 34 -> 22.
// Lane-local lsum (q = col); epilogue inv via shfl broadcast (r7-proven).
// LDS: sK 2x16KB + sVt 2x16KB + sP 8KB + scrL 256B -> 2 blocks/CU.
__launch_bounds__(256, 2)
__global__ void attn_kernel(const float* __restrict__ Q, const bf16_t* __restrict__ Kb,
                            const bf16_t* __restrict__ Vt, const int* __restrict__ VL,
                            const float* __restrict__ sufV, const int* __restrict__ sched,
                            float* __restrict__ Out) {
  __shared__ __align__(16) char smem[73984];
  bf16_t* sK = (bf16_t*)smem;                     // [2][64*128]
  bf16_t* sV = (bf16_t*)(smem + 32768);           // [2][128*64] (V^T tile)

  const int unit = sched[blockIdx.x];
  const int b  = (unit >> 5) & 15;
  const int qt = unit & 31;
  const int L  = load_valid_len(VL, b);
  const int ktiles = (L + 63) >> 6;

  const int tid = threadIdx.x;
  const int wave = tid >> 6;
  const int lane = tid & 63;
  const int col = lane & 15;
  const int quad = lane >> 4;
  const int wr = wave >> 1;   // q-half
  const int wc = wave & 1;    // key-half

  bf16_t* pw = (bf16_t*)(smem + 65536 + wave * 2048);  // P[16 qrow][8 chunk] 16B chunks

  // Q fragments: fp32 -> bf16 in-reg, scaled by log2(e)/sqrt(128) (log2 domain).
  // Used as the B-operand of the swapped QK (lane holds Q[q=col][d-chunk]).
  bf16x8 qf[2][4];
  {
    const float scq = 0.1275174307f;
#pragma unroll
    for (int m = 0; m < 2; ++m) {
      const float* qrow = Q + ((size_t)b * NQ + qt * 64 + wr * 32 + m * 16 + col) * DD + quad * 8;
#pragma unroll
      for (int ks = 0; ks < 4; ++ks) {
        float4 u0 = *(const float4*)(qrow + ks * 32);
        float4 u1 = *(const float4*)(qrow + ks * 32 + 4);
        bf16x8 f;
        f[0] = (bf16_t)(u0.x * scq); f[1] = (bf16_t)(u0.y * scq);
        f[2] = (bf16_t)(u0.z * scq); f[3] = (bf16_t)(u0.w * scq);
        f[4] = (bf16_t)(u1.x * scq); f[5] = (bf16_t)(u1.y * scq);
        f[6] = (bf16_t)(u1.z * scq); f[7] = (bf16_t)(u1.w * scq);
        qf[m][ks] = f;
      }
    }
  }

  const char* Kbyte = (const char*)Kb + (size_t)b * NK * DD * 2;
  const char* Vbyte = (const char*)Vt + (size_t)b * DVV * NK * 2;
  int koff[4], voff[4];
#pragma unroll
  for (int i = 0; i < 4; ++i) {
    int krow = wave * 16 + i * 4 + (lane >> 4);
    koff[i] = krow * 256 + (((lane & 15) ^ (krow & 15)) * 16);
    int vrow = wave * 32 + i * 8 + (lane >> 3);
    voff[i] = vrow * (NK * 2) + (((lane & 7) ^ ((lane >> 3) & 7)) * 16);
  }

  f32x4 Oacc[2][8];   // [m q-16-group][o dv-tile], partial over this wave's 32 keys
#pragma unroll
  for (int m = 0; m < 2; ++m)
#pragma unroll
    for (int o = 0; o < 8; ++o) Oacc[m][o] = (f32x4){0.f, 0.f, 0.f, 0.f};
  float lsum[2] = {0.f, 0.f};   // lane-local l for q = m*16 + col (this wave's keys)

  auto issueTile = [&](int kt, int bufi) {
    const char* kb = Kbyte + (size_t)kt * 16384;
    const char* vb = Vbyte + (size_t)kt * 128;
    bf16_t* kl = sK + bufi * 8192 + wave * 2048;
    bf16_t* vl = sV + bufi * 8192 + wave * 2048;
#pragma unroll
    for (int i = 0; i < 4; ++i) {
      gld16(kb + koff[i], kl + i * 512);
      gld16(vb + voff[i], vl + i * 512);
    }
  };

  if (ktiles > 0) issueTile(0, 0);
  int bufi = 0;
  for (int kt = 0; kt < ktiles; ++kt) {
    if (kt + 1 < ktiles) {
      issueTile(kt + 1, bufi ^ 1);
      asm volatile("s_waitcnt vmcnt(8)\n\ts_barrier" ::: "memory");
    } else {
      asm volatile("s_waitcnt vmcnt(0)\n\ts_barrier" ::: "memory");
    }

    const bf16_t* kb_ = sK + bufi * 8192;
    const bf16_t* vb_ = sV + bufi * 8192;

    // S^T = K Q^T (log2 domain): K-frag is the A-operand (rows = keys), qf the B-operand
    // (cols = q). Same LDS addresses as the proven forward path; 8 reads feed 16 MFMAs.
    f32x4 sc[2][2];   // [ntk][m]
#pragma unroll
    for (int ntk = 0; ntk < 2; ++ntk)
#pragma unroll
      for (int m = 0; m < 2; ++m) sc[ntk][m] = (f32x4){0.f, 0.f, 0.f, 0.f};
    __builtin_amdgcn_s_setprio(1);
#pragma unroll
    for (int ks = 0; ks < 4; ++ks) {
#pragma unroll
      for (int ntk = 0; ntk < 2; ++ntk) {
        bf16x8 kf = *(const bf16x8*)&kb_[(wc * 32 + ntk * 16 + col) * 128 + (((ks * 4 + quad) ^ col) * 8)];
        sc[ntk][0] = mfma16(kf, qf[0][ks], sc[ntk][0]);
        sc[ntk][1] = mfma16(kf, qf[1][ks], sc[ntk][1]);
      }
    }
    __builtin_amdgcn_s_setprio(0);

    // p = 2^S (lane holds S[key = kbase+ntk*16+quad*4+r][q = m*16+col]); mask, lane-local
    // l accum, pack 4 consecutive-key values -> one b64 write into the chunk-XOR P layout.
    // Writer chunk m*4+ntk*2+(quad>>1), elem (quad&1)*4+r <-> reader klocal quad*8+j.
    const int kbase = kt * 64 + wc * 32;
#pragma unroll
    for (int ntk = 0; ntk < 2; ++ntk) {
#pragma unroll
      for (int m = 0; m < 2; ++m) {
        float pv[4];
#pragma unroll
        for (int r = 0; r < 4; ++r) {
          float p = __builtin_amdgcn_exp2f(sc[ntk][m][r]);
          p = (kbase + ntk * 16 + quad * 4 + r < L) ? p : 0.f;
          lsum[m] += p;
          pv[r] = p;
        }
        int cidx = m * 4 + ntk * 2 + (quad >> 1);
        int phys = cidx ^ (col & 7);
        *(bf16x4*)&pw[col * 64 + phys * 8 + (quad & 1) * 4] =
            (bf16x4){(bf16_t)pv[0], (bf16_t)pv[1], (bf16_t)pv[2], (bf16_t)pv[3]};
      }
    }

    // O += P V over this wave's 32 keys: 2 A reads + 8 V reads feed 16 MFMAs (r3-proven)
    bf16x8 pa[2];
#pragma unroll
    for (int m = 0; m < 2; ++m)
      pa[m] = *(const bf16x8*)&pw[col * 64 + (((m * 4 + quad) ^ (col & 7)) * 8)];
    __builtin_amdgcn_s_setprio(1);
#pragma unroll
    for (int o = 0; o < 8; ++o) {
      bf16x8 bb = *(const bf16x8*)&vb_[(o * 16 + col) * 64 + (((wc * 4 + quad) ^ (col & 7)) * 8)];
      Oacc[0][o] = mfma16(pa[0], bb, Oacc[0][o]);
      Oacc[1][o] = mfma16(pa[1], bb, Oacc[1][o]);
    }
    __builtin_amdgcn_s_setprio(0);
    asm volatile("s_barrier" ::: "memory");
    bufi ^= 1;
  }

  // reduce l across the 4 quads sharing each q (lane-local per col)
#pragma unroll
  for (int m = 0; m < 2; ++m) {
    lsum[m] += __shfl_xor(lsum[m], 16, 64);
    lsum[m] += __shfl_xor(lsum[m], 32, 64);
  }

  // ---- cross-wave (key-half) merge via LDS scratch (aliases dead sK/sV) ----
  float* scrO = (float*)(smem + wr * 18432);
  float* scrL = (float*)(smem + 73728) + wr * 32;

  if (wc == 1) {
#pragma unroll
    for (int m = 0; m < 2; ++m)
#pragma unroll
      for (int o = 0; o < 8; ++o)
        *(f32x4*)&scrO[(o * 16 + col) * 36 + m * 16 + quad * 4] = Oacc[m][o];
    if (quad == 0) {
#pragma unroll
      for (int m = 0; m < 2; ++m) scrL[m * 16 + col] = lsum[m];
    }
  }
  __syncthreads();
  if (wc == 0) {
    // epilogue: masked-suffix closed form (e^{1e-8}==1.0f) + divide + direct store
    const float wmask = (float)(NK - L);
    float inv[2];
#pragma unroll
    for (int m = 0; m < 2; ++m)
      inv[m] = 1.0f / (lsum[m] + scrL[m * 16 + col] + wmask);   // q = m*16 + col
    float invq[2][4];
#pragma unroll
    for (int m = 0; m < 2; ++m)
#pragma unroll
      for (int r = 0; r < 4; ++r)
        invq[m][r] = __shfl(inv[m], quad * 4 + r, 64);          // q = m*16 + quad*4 + r
    const float* sfv = sufV + b * DVV;
    float* Ob = Out + ((size_t)b * NQ + qt * 64 + wr * 32) * DVV;
#pragma unroll
    for (int m = 0; m < 2; ++m)
#pragma unroll
      for (int o = 0; o < 8; ++o) {
        f32x4 part = *(const f32x4*)&scrO[(o * 16 + col) * 36 + m * 16 + quad * 4];
        float svv = sfv[o * 16 + col];
#pragma unroll
        for (int r = 0; r < 4; ++r)
          Ob[(size_t)(m * 16 + quad * 4 + r) * DVV + o * 16 + col] =
              (Oacc[m][o][r] + part[r] + svv) * invq[m][r];
      }
  }
}

// ================= fallback path (round-1 kernel) if ws too small =================
#define KSTR 152
#define VSTR 88
#define PSTR 72

__global__ void suffix_fb(const float* __restrict__ V, const int* __restrict__ VL,
                          float* __restrict__ ws) {
  int b = blockIdx.x;
  int kc = blockIdx.y;
  int L = load_valid_len(VL, b);
  int k0 = kc * 128, k1 = k0 + 128;
  int lo = max(L, k0);
  int t = threadIdx.x;
  int dv = t & 127;
  int h = t >> 7;
  float s = 0.f;
  for (int k = lo + h; k < k1; k += 2)
    s += V[((size_t)b * NK + k) * DVV + dv];
  __shared__ float part[128];
  if (h == 0) part[dv] = s;
  __syncthreads();
  if (h == 1) atomicAdd(&ws[b * DVV + dv], part[dv] + s);
}

__launch_bounds__(256, 2)
__global__ void attn_fb(const float* __restrict__ Q, const float* __restrict__ K,
                        const float* __restrict__ V, const int* __restrict__ VL,
                        const float* __restrict__ sufV, float* __restrict__ Out) {
  const int flat = blockIdx.x;
  const int b  = flat & 15;
  const int qt = flat >> 4;
  const int L  = load_valid_len(VL, b);

  __shared__ bf16_t sK2[64 * KSTR];
  __shared__ bf16_t sVT2[128 * VSTR];
  __shared__ bf16_t sP2[4 * 16 * PSTR];

  const int tid  = threadIdx.x;
  const int wave = tid >> 6;
  const int lane = tid & 63;
  const int col  = lane & 15;
  const int quad = lane >> 4;

  const float* Qb = Q + ((size_t)b * NQ + qt * 64 + wave * 16) * DD;
  const float* Kb = K + (size_t)b * NK * DD;
  const float* Vb = V + (size_t)b * NK * DVV;

  bf16x8 qf[4];
  {
    const float scq = 0.08838834764831845f;
    const float* qrow = Qb + (size_t)col * DD + quad * 8;
#pragma unroll
    for (int ks = 0; ks < 4; ++ks) {
      float4 u0 = *(const float4*)(qrow + ks * 32);
      float4 u1 = *(const float4*)(qrow + ks * 32 + 4);
      bf16x8 f;
      f[0] = (bf16_t)(u0.x * scq); f[1] = (bf16_t)(u0.y * scq);
      f[2] = (bf16_t)(u0.z * scq); f[3] = (bf16_t)(u0.w * scq);
      f[4] = (bf16_t)(u1.x * scq); f[5] = (bf16_t)(u1.y * scq);
      f[6] = (bf16_t)(u1.z * scq); f[7] = (bf16_t)(u1.w * scq);
      qf[ks] = f;
    }
  }

  f32x4 Oacc[8];
#pragma unroll
  for (int o = 0; o < 8; ++o) Oacc[o] = (f32x4){0.f, 0.f, 0.f, 0.f};
  float m_i[4], l_i[4];
#pragma unroll
  for (int r = 0; r < 4; ++r) { m_i[r] = -1e30f; l_i[r] = 0.f; }

  const int ktiles = (L + 63) >> 6;
  for (int kt = 0; kt < ktiles; ++kt) {
    {
      int r0 = tid >> 5;
      int d4 = (tid & 31) * 4;
      const float* src = Kb + ((size_t)(kt * 64) + r0) * DD + d4;
#pragma unroll
      for (int i = 0; i < 8; ++i) {
        float4 u = *(const float4*)(src + (size_t)i * 8 * DD);
        bf16x4 w4 = {(bf16_t)u.x, (bf16_t)u.y, (bf16_t)u.z, (bf16_t)u.w};
        *(bf16x4*)&sK2[(r0 + i * 8) * KSTR + d4] = w4;
      }
    }
    {
      int r2 = (tid & 31) * 2;
      int dbase = (tid >> 5) * 4;
#pragma unroll
      for (int i = 0; i < 4; ++i) {
        int d4 = dbase + i * 32;
        const float* s0 = Vb + ((size_t)(kt * 64) + r2) * DVV + d4;
        float4 u0 = *(const float4*)s0;
        float4 u1 = *(const float4*)(s0 + DVV);
        *(bf16x2*)&sVT2[(d4 + 0) * VSTR + r2] = (bf16x2){(bf16_t)u0.x, (bf16_t)u1.x};
        *(bf16x2*)&sVT2[(d4 + 1) * VSTR + r2] = (bf16x2){(bf16_t)u0.y, (bf16_t)u1.y};
        *(bf16x2*)&sVT2[(d4 + 2) * VSTR + r2] = (bf16x2){(bf16_t)u0.z, (bf16_t)u1.z};
        *(bf16x2*)&sVT2[(d4 + 3) * VSTR + r2] = (bf16x2){(bf16_t)u0.w, (bf16_t)u1.w};
      }
    }
    __syncthreads();

    f32x4 sv4[4];
#pragma unroll
    for (int nt = 0; nt < 4; ++nt) sv4[nt] = (f32x4){0.f, 0.f, 0.f, 0.f};
#pragma unroll
    for (int ks = 0; ks < 4; ++ks) {
      bf16x8 a = qf[ks];
#pragma unroll
      for (int nt = 0; nt < 4; ++nt) {
        bf16x8 bb = *(const bf16x8*)&sK2[(nt * 16 + col) * KSTR + ks * 32 + quad * 8];
        sv4[nt] = mfma16(a, bb, sv4[nt]);
      }
    }

    const int key0 = kt * 64;
    float sv[4][4];
    float mloc[4] = {-1e30f, -1e30f, -1e30f, -1e30f};
#pragma unroll
    for (int nt = 0; nt < 4; ++nt) {
      int key = key0 + nt * 16 + col;
      bool valid = key < L;
#pragma unroll
      for (int r = 0; r < 4; ++r) {
        float v = valid ? sv4[nt][r] : -1e30f;
        sv[nt][r] = v;
        mloc[r] = fmaxf(mloc[r], v);
      }
    }
#pragma unroll
    for (int off = 1; off < 16; off <<= 1)
#pragma unroll
      for (int r = 0; r < 4; ++r) mloc[r] = fmaxf(mloc[r], __shfl_xor(mloc[r], off, 64));
    float al[4];
#pragma unroll
    for (int r = 0; r < 4; ++r) {
      float mn = fmaxf(m_i[r], mloc[r]);
      al[r] = __expf(m_i[r] - mn);
      m_i[r] = mn;
    }
    float lloc[4] = {0.f, 0.f, 0.f, 0.f};
#pragma unroll
    for (int nt = 0; nt < 4; ++nt)
#pragma unroll
      for (int r = 0; r < 4; ++r) {
        float p = __expf(sv[nt][r] - m_i[r]);
        sv[nt][r] = p;
        lloc[r] += p;
      }
#pragma unroll
    for (int off = 1; off < 16; off <<= 1)
#pragma unroll
      for (int r = 0; r < 4; ++r) lloc[r] += __shfl_xor(lloc[r], off, 64);
#pragma unroll
    for (int r = 0; r < 4; ++r) l_i[r] = l_i[r] * al[r] + lloc[r];
#pragma unroll
    for (int o = 0; o < 8; ++o)
#pragma unroll
      for (int r = 0; r < 4; ++r) Oacc[o][r] *= al[r];

    bf16_t* pw = &sP2[wave * 16 * PSTR];
#pragma unroll
    for (int nt = 0; nt < 4; ++nt)
#pragma unroll
      for (int r = 0; r < 4; ++r)
        pw[(quad * 4 + r) * PSTR + nt * 16 + col] = (bf16_t)sv[nt][r];

#pragma unroll
    for (int ks2 = 0; ks2 < 2; ++ks2) {
      bf16x8 a = *(const bf16x8*)&pw[(lane & 15) * PSTR + ks2 * 32 + quad * 8];
#pragma unroll
      for (int o = 0; o < 8; ++o) {
        bf16x8 bb = *(const bf16x8*)&sVT2[(o * 16 + col) * VSTR + ks2 * 32 + quad * 8];
        Oacc[o] = mfma16(a, bb, Oacc[o]);
      }
    }
    __syncthreads();
  }

  if (L < NK) {
    const float c = 1e-8f;
    const float w = (float)(NK - L);
    float a2[4], ec[4];
#pragma unroll
    for (int r = 0; r < 4; ++r) {
      float mn = fmaxf(m_i[r], c);
      a2[r] = __expf(m_i[r] - mn);
      ec[r] = __expf(c - mn);
      l_i[r] = l_i[r] * a2[r] + w * ec[r];
    }
    const float* sfv = sufV + b * DVV;
#pragma unroll
    for (int o = 0; o < 8; ++o) {
      float svv = sfv[o * 16 + col];
#pragma unroll
      for (int r = 0; r < 4; ++r) Oacc[o][r] = Oacc[o][r] * a2[r] + ec[r] * svv;
    }
  }

  float invl[4];
#pragma unroll
  for (int r = 0; r < 4; ++r) invl[r] = 1.0f / l_i[r];

  float* Ob = Out + ((size_t)b * NQ + qt * 64 + wave * 16) * DVV;
#pragma unroll
  for (int o = 0; o < 8; ++o)
#pragma unroll
    for (int r = 0; r < 4; ++r)
      Ob[(size_t)(quad * 4 + r) * DVV + o * 16 + col] = Oacc[o][r] * invl[r];
}

extern "C" void kernel_launch(void* const* d_in, const int* in_sizes, int n_in,
                              void* d_out, int out_size, void* d_ws, size_t ws_size,
                              hipStream_t stream) {
  const float* Q  = (const float*)d_in[0];
  const float* K  = (const float*)d_in[1];
  const float* V  = (const float*)d_in[2];
  const int*   VL = (const int*)d_in[3];
  float* out = (float*)d_out;

  if (ws_size >= WS_NEED) {
    char* ws = (char*)d_ws;
    bf16_t* Kb = (bf16_t*)(ws + KB_OFF);
    bf16_t* Vt = (bf16_t*)(ws + VT_OFF);
    float* sufV = (float*)(ws + SUF_OFF);
    int* sched = (int*)(ws + SCH_OFF);

    hipMemsetAsync(sufV, 0, BATCH * DVV * sizeof(float), stream);
    prep_kernel<<<1025, 256, 0, stream>>>(K, V, VL, Kb, Vt, sufV, sched);
    attn_kernel<<<512, 256, 0, stream>>>(Q, Kb, Vt, VL, sufV, sched, out);
  } else {
    float* ws = (float*)d_ws;
    hipMemsetAsync(ws, 0, BATCH * DVV * sizeof(float), stream);
    dim3 g1(BATCH, 16);
    suffix_fb<<<g1, 256, 0, stream>>>(V, VL, ws);
    attn_fb<<<BATCH * (NQ / 64), 256, 0, stream>>>(Q, K, V, VL, ws, out);
  }
}

// Round 9
// 134.732 us; speedup vs baseline: 1.0502x; 1.0147x over previous
//
#include <hip/hip_runtime.h>
#include <stdint.h>

#define BATCH 16
#define NQ    2048
#define NK    2048
#define DD    128
#define DVV   128

typedef __bf16 bf16_t;
typedef __bf16 bf16x2 __attribute__((ext_vector_type(2)));
typedef __bf16 bf16x4 __attribute__((ext_vector_type(4)));
typedef __bf16 bf16x8 __attribute__((ext_vector_type(8)));
typedef float  f32x4  __attribute__((ext_vector_type(4)));

// ---------------- ws layout (bytes) ----------------
#define KB_OFF   ((size_t)0)                 // bf16 K: 8 MB
#define VT_OFF   ((size_t)8 * 1024 * 1024)   // bf16 V^T [b][dv][k]: 8 MB
#define SUF_OFF  ((size_t)16 * 1024 * 1024)  // fp32 sufV[b][dv]: 8 KB
#define SCH_OFF  (SUF_OFF + 65536)           // int schedule[512]
#define WS_NEED  (SCH_OFF + 4096)

__device__ __forceinline__ int load_valid_len(const int* VL, int b) {
  bool looks64 = true;
#pragma unroll
  for (int i = 0; i < 16; ++i) {
    int hi = VL[2 * i + 1];
    unsigned lo = (unsigned)VL[2 * i];
    looks64 = looks64 && (hi == 0) && (lo <= 2048u);
  }
  int L = looks64 ? VL[2 * b] : VL[b];
  return min(max(L, 0), NK);
}

__device__ __forceinline__ void gld16(const void* g, void* l) {
  __builtin_amdgcn_global_load_lds(
      (const __attribute__((address_space(1))) unsigned int*)g,
      (__attribute__((address_space(3))) unsigned int*)l, 16, 0, 0);
}

__device__ __forceinline__ f32x4 mfma16(bf16x8 a, bf16x8 b, f32x4 c) {
  return __builtin_amdgcn_mfma_f32_16x16x32_bf16(a, b, c, 0, 0, 0);
}

// ---------------- fused preprocessing ----------------
// blocks 0..511  : K fp32 -> bf16 (coalesced, lane-interleaved)
// blocks 512..1023: V fp32 [b][k][dv] -> bf16 V^T [b][dv][k] + masked-suffix sums
//                   (suffix shfl-tree GUARDED: only blocks touching masked keys)
// block 1024     : snake schedule (batches sorted by L desc)
__global__ void prep_kernel(const float* __restrict__ K, const float* __restrict__ V,
                            const int* __restrict__ VL,
                            bf16_t* __restrict__ Kb, bf16_t* __restrict__ Vt,
                            float* __restrict__ sufV, int* __restrict__ sched) {
  __shared__ bf16_t tile[128 * 72];  // [dv][key] stride 72
  __shared__ int bs[16];
  const int bid = blockIdx.x;
  const int t = threadIdx.x;
  if (bid < 512) {
    // ---- K convert: thread owns float4 pair (2t,2t+1) of 512-float4 chunks ----
#pragma unroll
    for (int i = 0; i < 4; ++i) {
      size_t f4 = (size_t)bid * 2048 + (size_t)i * 512 + 2 * t;
      float4 a = ((const float4*)K)[f4];
      float4 c = ((const float4*)K)[f4 + 1];
      bf16x8 o;
      o[0] = (bf16_t)a.x; o[1] = (bf16_t)a.y; o[2] = (bf16_t)a.z; o[3] = (bf16_t)a.w;
      o[4] = (bf16_t)c.x; o[5] = (bf16_t)c.y; o[6] = (bf16_t)c.z; o[7] = (bf16_t)c.w;
      ((bf16x8*)Kb)[f4 >> 1] = o;
    }
    return;
  }
  if (bid < 1024) {
    // ---- vtrans (proven path; suffix tree now guarded) ----
    int v = bid - 512;
    int b = v & 15, kt = v >> 4;
    int L = load_valid_len(VL, b);
    int m = t & 31;   // key-pair 0..31
    int g = t >> 5;   // dv group 0..7
    int r2 = m * 2;
    int k0g = kt * 64 + r2;
    const float* src = V + ((size_t)b * NK + k0g) * DVV;
    float sacc[4][4];
#pragma unroll
    for (int i = 0; i < 4; ++i)
#pragma unroll
      for (int j = 0; j < 4; ++j) sacc[i][j] = 0.f;
    bool a0 = (k0g >= L), a1 = (k0g + 1 >= L);
#pragma unroll
    for (int i = 0; i < 4; ++i) {
      int d4 = g * 4 + i * 32;
      float4 u0 = *(const float4*)(src + d4);
      float4 u1 = *(const float4*)(src + DVV + d4);
      *(bf16x2*)&tile[(d4 + 0) * 72 + r2] = (bf16x2){(bf16_t)u0.x, (bf16_t)u1.x};
      *(bf16x2*)&tile[(d4 + 1) * 72 + r2] = (bf16x2){(bf16_t)u0.y, (bf16_t)u1.y};
      *(bf16x2*)&tile[(d4 + 2) * 72 + r2] = (bf16x2){(bf16_t)u0.z, (bf16_t)u1.z};
      *(bf16x2*)&tile[(d4 + 3) * 72 + r2] = (bf16x2){(bf16_t)u0.w, (bf16_t)u1.w};
      if (a0) { sacc[i][0] += u0.x; sacc[i][1] += u0.y; sacc[i][2] += u0.z; sacc[i][3] += u0.w; }
      if (a1) { sacc[i][0] += u1.x; sacc[i][1] += u1.y; sacc[i][2] += u1.z; sacc[i][3] += u1.w; }
    }
    __syncthreads();
    if (kt * 64 + 64 > L) {   // block-uniform: touches masked keys
#pragma unroll
      for (int off = 1; off < 32; off <<= 1)
#pragma unroll
        for (int i = 0; i < 4; ++i)
#pragma unroll
          for (int j = 0; j < 4; ++j) sacc[i][j] += __shfl_xor(sacc[i][j], off, 64);
      if (m == 0) {
#pragma unroll
        for (int i = 0; i < 4; ++i)
#pragma unroll
          for (int j = 0; j < 4; ++j)
            atomicAdd(&sufV[b * 128 + g * 4 + i * 32 + j], sacc[i][j]);
      }
    }
    int dv = t >> 1, half = t & 1;
    bf16_t* dst = Vt + (size_t)b * DVV * NK + (size_t)dv * NK + kt * 64 + half * 32;
    const bf16_t* srow = &tile[dv * 72 + half * 32];
#pragma unroll
    for (int j = 0; j < 4; ++j)
      *(bf16x8*)(dst + j * 8) = *(const bf16x8*)(srow + j * 8);
    return;
  }
  // ---- schedule block ----
  if (t == 0) {
    int Ls[16], idx[16];
#pragma unroll
    for (int i = 0; i < 16; ++i) { Ls[i] = load_valid_len(VL, i); idx[i] = i; }
    for (int i = 1; i < 16; ++i) {       // insertion sort desc by L
      int lv = Ls[i], iv = idx[i], j = i - 1;
      while (j >= 0 && Ls[j] < lv) { Ls[j + 1] = Ls[j]; idx[j + 1] = idx[j]; --j; }
      Ls[j + 1] = lv; idx[j + 1] = iv;
    }
#pragma unroll
    for (int i = 0; i < 16; ++i) bs[i] = idx[i];
  }
  __syncthreads();
  for (int j = t; j < 512; j += 256) {
    int r = (j < 256) ? j : (767 - j);    // snake pairing: blocks j, j+256 share a CU slot
    sched[j] = (bs[r >> 5] << 5) | (r & 31);
  }
}

// ---------------- main attention ----------------
// 2x2 wave tiling (32q x 32k per wave). SWAPPED QK^T (r7/r8-proven) + b64 P store into
// chunk-XOR layout (r8-proven). NEW: single-barrier iteration -- prefetch issue moved
// AFTER the barrier (provably safe: all waves past barrier => done with bufi^1), so the
// end-of-iteration barrier is deleted. 2 barriers/iter -> 1.
// LDS: sK 2x16KB + sVt 2x16KB + sP 8KB + scrL 256B -> 2 blocks/CU.
__launch_bounds__(256, 2)
__global__ void attn_kernel(const float* __restrict__ Q, const bf16_t* __restrict__ Kb,
                            const bf16_t* __restrict__ Vt, const int* __restrict__ VL,
                            const float* __restrict__ sufV, const int* __restrict__ sched,
                            float* __restrict__ Out) {
  __shared__ __align__(16) char smem[73984];
  bf16_t* sK = (bf16_t*)smem;                     // [2][64*128]
  bf16_t* sV = (bf16_t*)(smem + 32768);           // [2][128*64] (V^T tile)

  const int unit = sched[blockIdx.x];
  const int b  = (unit >> 5) & 15;
  const int qt = unit & 31;
  const int L  = load_valid_len(VL, b);
  const int ktiles = (L + 63) >> 6;

  const int tid = threadIdx.x;
  const int wave = tid >> 6;
  const int lane = tid & 63;
  const int col = lane & 15;
  const int quad = lane >> 4;
  const int wr = wave >> 1;   // q-half
  const int wc = wave & 1;    // key-half

  bf16_t* pw = (bf16_t*)(smem + 65536 + wave * 2048);  // P[16 qrow][8 chunk] 16B chunks

  // Q fragments: fp32 -> bf16 in-reg, scaled by log2(e)/sqrt(128) (log2 domain).
  // Used as the B-operand of the swapped QK (lane holds Q[q=col][d-chunk]).
  bf16x8 qf[2][4];
  {
    const float scq = 0.1275174307f;
#pragma unroll
    for (int m = 0; m < 2; ++m) {
      const float* qrow = Q + ((size_t)b * NQ + qt * 64 + wr * 32 + m * 16 + col) * DD + quad * 8;
#pragma unroll
      for (int ks = 0; ks < 4; ++ks) {
        float4 u0 = *(const float4*)(qrow + ks * 32);
        float4 u1 = *(const float4*)(qrow + ks * 32 + 4);
        bf16x8 f;
        f[0] = (bf16_t)(u0.x * scq); f[1] = (bf16_t)(u0.y * scq);
        f[2] = (bf16_t)(u0.z * scq); f[3] = (bf16_t)(u0.w * scq);
        f[4] = (bf16_t)(u1.x * scq); f[5] = (bf16_t)(u1.y * scq);
        f[6] = (bf16_t)(u1.z * scq); f[7] = (bf16_t)(u1.w * scq);
        qf[m][ks] = f;
      }
    }
  }

  const char* Kbyte = (const char*)Kb + (size_t)b * NK * DD * 2;
  const char* Vbyte = (const char*)Vt + (size_t)b * DVV * NK * 2;
  int koff[4], voff[4];
#pragma unroll
  for (int i = 0; i < 4; ++i) {
    int krow = wave * 16 + i * 4 + (lane >> 4);
    koff[i] = krow * 256 + (((lane & 15) ^ (krow & 15)) * 16);
    int vrow = wave * 32 + i * 8 + (lane >> 3);
    voff[i] = vrow * (NK * 2) + (((lane & 7) ^ ((lane >> 3) & 7)) * 16);
  }

  f32x4 Oacc[2][8];   // [m q-16-group][o dv-tile], partial over this wave's 32 keys
#pragma unroll
  for (int m = 0; m < 2; ++m)
#pragma unroll
    for (int o = 0; o < 8; ++o) Oacc[m][o] = (f32x4){0.f, 0.f, 0.f, 0.f};
  float lsum[2] = {0.f, 0.f};   // lane-local l for q = m*16 + col (this wave's keys)

  auto issueTile = [&](int kt, int bufi) {
    const char* kb = Kbyte + (size_t)kt * 16384;
    const char* vb = Vbyte + (size_t)kt * 128;
    bf16_t* kl = sK + bufi * 8192 + wave * 2048;
    bf16_t* vl = sV + bufi * 8192 + wave * 2048;
#pragma unroll
    for (int i = 0; i < 4; ++i) {
      gld16(kb + koff[i], kl + i * 512);
      gld16(vb + voff[i], vl + i * 512);
    }
  };

  if (ktiles > 0) issueTile(0, 0);
  int bufi = 0;
  for (int kt = 0; kt < ktiles; ++kt) {
    // Single barrier per iteration: drain my outstanding DMA, converge, THEN issue the
    // next prefetch (safe: all waves past this barrier are done reading bufi^1).
    asm volatile("s_waitcnt vmcnt(0)\n\ts_barrier" ::: "memory");
    if (kt + 1 < ktiles) issueTile(kt + 1, bufi ^ 1);

    const bf16_t* kb_ = sK + bufi * 8192;
    const bf16_t* vb_ = sV + bufi * 8192;

    // S^T = K Q^T (log2 domain): K-frag is the A-operand (rows = keys), qf the B-operand
    // (cols = q). Same LDS addresses as the proven forward path; 8 reads feed 16 MFMAs.
    f32x4 sc[2][2];   // [ntk][m]
#pragma unroll
    for (int ntk = 0; ntk < 2; ++ntk)
#pragma unroll
      for (int m = 0; m < 2; ++m) sc[ntk][m] = (f32x4){0.f, 0.f, 0.f, 0.f};
    __builtin_amdgcn_s_setprio(1);
#pragma unroll
    for (int ks = 0; ks < 4; ++ks) {
#pragma unroll
      for (int ntk = 0; ntk < 2; ++ntk) {
        bf16x8 kf = *(const bf16x8*)&kb_[(wc * 32 + ntk * 16 + col) * 128 + (((ks * 4 + quad) ^ col) * 8)];
        sc[ntk][0] = mfma16(kf, qf[0][ks], sc[ntk][0]);
        sc[ntk][1] = mfma16(kf, qf[1][ks], sc[ntk][1]);
      }
    }
    __builtin_amdgcn_s_setprio(0);

    // p = 2^S (lane holds S[key = kbase+ntk*16+quad*4+r][q = m*16+col]); mask, lane-local
    // l accum, pack 4 consecutive-key values -> one b64 write into the chunk-XOR P layout.
    const int kbase = kt * 64 + wc * 32;
#pragma unroll
    for (int ntk = 0; ntk < 2; ++ntk) {
#pragma unroll
      for (int m = 0; m < 2; ++m) {
        float pv[4];
#pragma unroll
        for (int r = 0; r < 4; ++r) {
          float p = __builtin_amdgcn_exp2f(sc[ntk][m][r]);
          p = (kbase + ntk * 16 + quad * 4 + r < L) ? p : 0.f;
          lsum[m] += p;
          pv[r] = p;
        }
        int cidx = m * 4 + ntk * 2 + (quad >> 1);
        int phys = cidx ^ (col & 7);
        *(bf16x4*)&pw[col * 64 + phys * 8 + (quad & 1) * 4] =
            (bf16x4){(bf16_t)pv[0], (bf16_t)pv[1], (bf16_t)pv[2], (bf16_t)pv[3]};
      }
    }

    // O += P V over this wave's 32 keys: 2 A reads + 8 V reads feed 16 MFMAs (r3-proven)
    bf16x8 pa[2];
#pragma unroll
    for (int m = 0; m < 2; ++m)
      pa[m] = *(const bf16x8*)&pw[col * 64 + (((m * 4 + quad) ^ (col & 7)) * 8)];
    __builtin_amdgcn_s_setprio(1);
#pragma unroll
    for (int o = 0; o < 8; ++o) {
      bf16x8 bb = *(const bf16x8*)&vb_[(o * 16 + col) * 64 + (((wc * 4 + quad) ^ (col & 7)) * 8)];
      Oacc[0][o] = mfma16(pa[0], bb, Oacc[0][o]);
      Oacc[1][o] = mfma16(pa[1], bb, Oacc[1][o]);
    }
    __builtin_amdgcn_s_setprio(0);
    bufi ^= 1;
  }
  __syncthreads();   // all waves done with sK/sV before epilogue scratch aliases them

  // reduce l across the 4 quads sharing each q (lane-local per col)
#pragma unroll
  for (int m = 0; m < 2; ++m) {
    lsum[m] += __shfl_xor(lsum[m], 16, 64);
    lsum[m] += __shfl_xor(lsum[m], 32, 64);
  }

  // ---- cross-wave (key-half) merge via LDS scratch (aliases dead sK/sV) ----
  float* scrO = (float*)(smem + wr * 18432);
  float* scrL = (float*)(smem + 73728) + wr * 32;

  if (wc == 1) {
#pragma unroll
    for (int m = 0; m < 2; ++m)
#pragma unroll
      for (int o = 0; o < 8; ++o)
        *(f32x4*)&scrO[(o * 16 + col) * 36 + m * 16 + quad * 4] = Oacc[m][o];
    if (quad == 0) {
#pragma unroll
      for (int m = 0; m < 2; ++m) scrL[m * 16 + col] = lsum[m];
    }
  }
  __syncthreads();
  if (wc == 0) {
    // epilogue: masked-suffix closed form (e^{1e-8}==1.0f) + divide + direct store
    const float wmask = (float)(NK - L);
    float inv[2];
#pragma unroll
    for (int m = 0; m < 2; ++m)
      inv[m] = 1.0f / (lsum[m] + scrL[m * 16 + col] + wmask);   // q = m*16 + col
    float invq[2][4];
#pragma unroll
    for (int m = 0; m < 2; ++m)
#pragma unroll
      for (int r = 0; r < 4; ++r)
        invq[m][r] = __shfl(inv[m], quad * 4 + r, 64);          // q = m*16 + quad*4 + r
    const float* sfv = sufV + b * DVV;
    float* Ob = Out + ((size_t)b * NQ + qt * 64 + wr * 32) * DVV;
#pragma unroll
    for (int m = 0; m < 2; ++m)
#pragma unroll
      for (int o = 0; o < 8; ++o) {
        f32x4 part = *(const f32x4*)&scrO[(o * 16 + col) * 36 + m * 16 + quad * 4];
        float svv = sfv[o * 16 + col];
#pragma unroll
        for (int r = 0; r < 4; ++r)
          Ob[(size_t)(m * 16 + quad * 4 + r) * DVV + o * 16 + col] =
              (Oacc[m][o][r] + part[r] + svv) * invq[m][r];
      }
  }
}

// ================= fallback path (round-1 kernel) if ws too small =================
#define KSTR 152
#define VSTR 88
#define PSTR 72

__global__ void suffix_fb(const float* __restrict__ V, const int* __restrict__ VL,
                          float* __restrict__ ws) {
  int b = blockIdx.x;
  int kc = blockIdx.y;
  int L = load_valid_len(VL, b);
  int k0 = kc * 128, k1 = k0 + 128;
  int lo = max(L, k0);
  int t = threadIdx.x;
  int dv = t & 127;
  int h = t >> 7;
  float s = 0.f;
  for (int k = lo + h; k < k1; k += 2)
    s += V[((size_t)b * NK + k) * DVV + dv];
  __shared__ float part[128];
  if (h == 0) part[dv] = s;
  __syncthreads();
  if (h == 1) atomicAdd(&ws[b * DVV + dv], part[dv] + s);
}

__launch_bounds__(256, 2)
__global__ void attn_fb(const float* __restrict__ Q, const float* __restrict__ K,
                        const float* __restrict__ V, const int* __restrict__ VL,
                        const float* __restrict__ sufV, float* __restrict__ Out) {
  const int flat = blockIdx.x;
  const int b  = flat & 15;
  const int qt = flat >> 4;
  const int L  = load_valid_len(VL, b);

  __shared__ bf16_t sK2[64 * KSTR];
  __shared__ bf16_t sVT2[128 * VSTR];
  __shared__ bf16_t sP2[4 * 16 * PSTR];

  const int tid  = threadIdx.x;
  const int wave = tid >> 6;
  const int lane = tid & 63;
  const int col  = lane & 15;
  const int quad = lane >> 4;

  const float* Qb = Q + ((size_t)b * NQ + qt * 64 + wave * 16) * DD;
  const float* Kb = K + (size_t)b * NK * DD;
  const float* Vb = V + (size_t)b * NK * DVV;

  bf16x8 qf[4];
  {
    const float scq = 0.08838834764831845f;
    const float* qrow = Qb + (size_t)col * DD + quad * 8;
#pragma unroll
    for (int ks = 0; ks < 4; ++ks) {
      float4 u0 = *(const float4*)(qrow + ks * 32);
      float4 u1 = *(const float4*)(qrow + ks * 32 + 4);
      bf16x8 f;
      f[0] = (bf16_t)(u0.x * scq); f[1] = (bf16_t)(u0.y * scq);
      f[2] = (bf16_t)(u0.z * scq); f[3] = (bf16_t)(u0.w * scq);
      f[4] = (bf16_t)(u1.x * scq); f[5] = (bf16_t)(u1.y * scq);
      f[6] = (bf16_t)(u1.z * scq); f[7] = (bf16_t)(u1.w * scq);
      qf[ks] = f;
    }
  }

  f32x4 Oacc[8];
#pragma unroll
  for (int o = 0; o < 8; ++o) Oacc[o] = (f32x4){0.f, 0.f, 0.f, 0.f};
  float m_i[4], l_i[4];
#pragma unroll
  for (int r = 0; r < 4; ++r) { m_i[r] = -1e30f; l_i[r] = 0.f; }

  const int ktiles = (L + 63) >> 6;
  for (int kt = 0; kt < ktiles; ++kt) {
    {
      int r0 = tid >> 5;
      int d4 = (tid & 31) * 4;
      const float* src = Kb + ((size_t)(kt * 64) + r0) * DD + d4;
#pragma unroll
      for (int i = 0; i < 8; ++i) {
        float4 u = *(const float4*)(src + (size_t)i * 8 * DD);
        bf16x4 w4 = {(bf16_t)u.x, (bf16_t)u.y, (bf16_t)u.z, (bf16_t)u.w};
        *(bf16x4*)&sK2[(r0 + i * 8) * KSTR + d4] = w4;
      }
    }
    {
      int r2 = (tid & 31) * 2;
      int dbase = (tid >> 5) * 4;
#pragma unroll
      for (int i = 0; i < 4; ++i) {
        int d4 = dbase + i * 32;
        const float* s0 = Vb + ((size_t)(kt * 64) + r2) * DVV + d4;
        float4 u0 = *(const float4*)s0;
        float4 u1 = *(const float4*)(s0 + DVV);
        *(bf16x2*)&sVT2[(d4 + 0) * VSTR + r2] = (bf16x2){(bf16_t)u0.x, (bf16_t)u1.x};
        *(bf16x2*)&sVT2[(d4 + 1) * VSTR + r2] = (bf16x2){(bf16_t)u0.y, (bf16_t)u1.y};
        *(bf16x2*)&sVT2[(d4 + 2) * VSTR + r2] = (bf16x2){(bf16_t)u0.z, (bf16_t)u1.z};
        *(bf16x2*)&sVT2[(d4 + 3) * VSTR + r2] = (bf16x2){(bf16_t)u0.w, (bf16_t)u1.w};
      }
    }
    __syncthreads();

    f32x4 sv4[4];
#pragma unroll
    for (int nt = 0; nt < 4; ++nt) sv4[nt] = (f32x4){0.f, 0.f, 0.f, 0.f};
#pragma unroll
    for (int ks = 0; ks < 4; ++ks) {
      bf16x8 a = qf[ks];
#pragma unroll
      for (int nt = 0; nt < 4; ++nt) {
        bf16x8 bb = *(const bf16x8*)&sK2[(nt * 16 + col) * KSTR + ks * 32 + quad * 8];
        sv4[nt] = mfma16(a, bb, sv4[nt]);
      }
    }

    const int key0 = kt * 64;
    float sv[4][4];
    float mloc[4] = {-1e30f, -1e30f, -1e30f, -1e30f};
#pragma unroll
    for (int nt = 0; nt < 4; ++nt) {
      int key = key0 + nt * 16 + col;
      bool valid = key < L;
#pragma unroll
      for (int r = 0; r < 4; ++r) {
        float v = valid ? sv4[nt][r] : -1e30f;
        sv[nt][r] = v;
        mloc[r] = fmaxf(mloc[r], v);
      }
    }
#pragma unroll
    for (int off = 1; off < 16; off <<= 1)
#pragma unroll
      for (int r = 0; r < 4; ++r) mloc[r] = fmaxf(mloc[r], __shfl_xor(mloc[r], off, 64));
    float al[4];
#pragma unroll
    for (int r = 0; r < 4; ++r) {
      float mn = fmaxf(m_i[r], mloc[r]);
      al[r] = __expf(m_i[r] - mn);
      m_i[r] = mn;
    }
    float lloc[4] = {0.f, 0.f, 0.f, 0.f};
#pragma unroll
    for (int nt = 0; nt < 4; ++nt)
#pragma unroll
      for (int r = 0; r < 4; ++r) {
        float p = __expf(sv[nt][r] - m_i[r]);
        sv[nt][r] = p;
        lloc[r] += p;
      }
#pragma unroll
    for (int off = 1; off < 16; off <<= 1)
#pragma unroll
      for (int r = 0; r < 4; ++r) lloc[r] += __shfl_xor(lloc[r], off, 64);
#pragma unroll
    for (int r = 0; r < 4; ++r) l_i[r] = l_i[r] * al[r] + lloc[r];
#pragma unroll
    for (int o = 0; o < 8; ++o)
#pragma unroll
      for (int r = 0; r < 4; ++r) Oacc[o][r] *= al[r];

    bf16_t* pw = &sP2[wave * 16 * PSTR];
#pragma unroll
    for (int nt = 0; nt < 4; ++nt)
#pragma unroll
      for (int r = 0; r < 4; ++r)
        pw[(quad * 4 + r) * PSTR + nt * 16 + col] = (bf16_t)sv[nt][r];

#pragma unroll
    for (int ks2 = 0; ks2 < 2; ++ks2) {
      bf16x8 a = *(const bf16x8*)&pw[(lane & 15) * PSTR + ks2 * 32 + quad * 8];
#pragma unroll
      for (int o = 0; o < 8; ++o) {
        bf16x8 bb = *(const bf16x8*)&sVT2[(o * 16 + col) * VSTR + ks2 * 32 + quad * 8];
        Oacc[o] = mfma16(a, bb, Oacc[o]);
      }
    }
    __syncthreads();
  }

  if (L < NK) {
    const float c = 1e-8f;
    const float w = (float)(NK - L);
    float a2[4], ec[4];
#pragma unroll
    for (int r = 0; r < 4; ++r) {
      float mn = fmaxf(m_i[r], c);
      a2[r] = __expf(m_i[r] - mn);
      ec[r] = __expf(c - mn);
      l_i[r] = l_i[r] * a2[r] + w * ec[r];
    }
    const float* sfv = sufV + b * DVV;
#pragma unroll
    for (int o = 0; o < 8; ++o) {
      float svv = sfv[o * 16 + col];
#pragma unroll
      for (int r = 0; r < 4; ++r) Oacc[o][r] = Oacc[o][r] * a2[r] + ec[r] * svv;
    }
  }

  float invl[4];
#pragma unroll
  for (int r = 0; r < 4; ++r) invl[r] = 1.0f / l_i[r];

  float* Ob = Out + ((size_t)b * NQ + qt * 64 + wave * 16) * DVV;
#pragma unroll
  for (int o = 0; o < 8; ++o)
#pragma unroll
    for (int r = 0; r < 4; ++r)
      Ob[(size_t)(quad * 4 + r) * DVV + o * 16 + col] = Oacc[o][r] * invl[r];
}

extern "C" void kernel_launch(void* const* d_in, const int* in_sizes, int n_in,
                              void* d_out, int out_size, void* d_ws, size_t ws_size,
                              hipStream_t stream) {
  const float* Q  = (const float*)d_in[0];
  const float* K  = (const float*)d_in[1];
  const float* V  = (const float*)d_in[2];
  const int*   VL = (const int*)d_in[3];
  float* out = (float*)d_out;

  if (ws_size >= WS_NEED) {
    char* ws = (char*)d_ws;
    bf16_t* Kb = (bf16_t*)(ws + KB_OFF);
    bf16_t* Vt = (bf16_t*)(ws + VT_OFF);
    float* sufV = (float*)(ws + SUF_OFF);
    int* sched = (int*)(ws + SCH_OFF);

    hipMemsetAsync(sufV, 0, BATCH * DVV * sizeof(float), stream);
    prep_kernel<<<1025, 256, 0, stream>>>(K, V, VL, Kb, Vt, sufV, sched);
    attn_kernel<<<512, 256, 0, stream>>>(Q, Kb, Vt, VL, sufV, sched, out);
  } else {
    float* ws = (float*)d_ws;
    hipMemsetAsync(ws, 0, BATCH * DVV * sizeof(float), stream);
    dim3 g1(BATCH, 16);
    suffix_fb<<<g1, 256, 0, stream>>>(V, VL, ws);
    attn_fb<<<BATCH * (NQ / 64), 256, 0, stream>>>(Q, K, V, VL, ws, out);
  }
}